// Round 15
// baseline (412.060 us; speedup 1.0000x reference)
//
#include <hip/hip_runtime.h>
#include <hip/hip_bf16.h>
#include <stdint.h>

typedef unsigned short u16;
typedef unsigned int u32;
typedef __bf16 bf16x8 __attribute__((ext_vector_type(8)));
typedef float f32x4 __attribute__((ext_vector_type(4)));
typedef float f32x16 __attribute__((ext_vector_type(16)));
typedef u16 u16x8 __attribute__((ext_vector_type(8)));

#define S_LEN 2048
#define DMODEL 4096
#define NHEADS 32
#define NKVH 8
#define DHEAD 128
#define LDQK 6144   // row stride of fused QKV activation buffer

__device__ __forceinline__ float bf2f(u16 x) {
    union { u32 i; float f; } u; u.i = ((u32)x) << 16; return u.f;
}
__device__ __forceinline__ u16 f2bf(float f) {
    union { float f; u32 i; } u; u.f = f;
    u32 x = u.i;
    return (u16)((x + 0x7fffu + ((x >> 16) & 1u)) >> 16);
}
__device__ __forceinline__ bf16x8 ld_bf8(const void* p) {
    int4 v = *(const int4*)p;
    return __builtin_bit_cast(bf16x8, v);
}

// ---------------- fp32 -> bf16 elementwise ----------------
__global__ void k_cvt(const float* __restrict__ in, u16* __restrict__ out, int n8) {
    int i = blockIdx.x * 256 + threadIdx.x;
    if (i >= n8) return;
    const float4* p = (const float4*)in + (size_t)i * 2;
    float4 a = p[0], b = p[1];
    u16x8 o;
    o[0]=f2bf(a.x); o[1]=f2bf(a.y); o[2]=f2bf(a.z); o[3]=f2bf(a.w);
    o[4]=f2bf(b.x); o[5]=f2bf(b.y); o[6]=f2bf(b.z); o[7]=f2bf(b.w);
    *((u16x8*)out + i) = o;
}

// ---------------- fast weight transpose: fp32 in[R][C] -> bf16 out[C][R] ----------------
__global__ __launch_bounds__(256)
void k_transpose_w(const float* __restrict__ in, u16* __restrict__ out, int R, int C) {
    __shared__ u16 tile[64][68];
    const int c0 = blockIdx.x * 64, r0 = blockIdx.y * 64;
    const int tid = threadIdx.x, lane = tid & 63, wid = tid >> 6;

    const int ch = lane & 15;
    const int rr = (lane >> 4) + wid * 4;
    #pragma unroll
    for (int it = 0; it < 4; it++) {
        int r = rr + it * 16;
        float4 v = *(const float4*)(in + (size_t)(r0 + r) * C + c0 + ch * 4);
        u16* t = &tile[r][ch * 4];
        t[0] = f2bf(v.x); t[1] = f2bf(v.y); t[2] = f2bf(v.z); t[3] = f2bf(v.w);
    }
    __syncthreads();
    const int k8 = lane & 7;
    const int cb = (lane >> 3) + wid * 8;
    #pragma unroll
    for (int it = 0; it < 2; it++) {
        int c = cb + it * 32;
        u16x8 o;
        #pragma unroll
        for (int i = 0; i < 8; i++) o[i] = tile[k8 * 8 + i][c];
        *(u16x8*)(out + (size_t)(c0 + c) * R + r0 + k8 * 8) = o;
    }
}

// ---------------- transpose u16 (V^T only) ----------------
template<typename TIN>
__global__ void k_transpose_bf16(const TIN* __restrict__ in, u16* __restrict__ out,
                                 int R, int C, int ldin) {
    __shared__ u16 tile[32][33];
    int c0 = blockIdx.x * 32, r0 = blockIdx.y * 32;
    int tx = threadIdx.x & 31, ty = threadIdx.x >> 5;
    #pragma unroll
    for (int i = 0; i < 4; i++) {
        int r = ty + i * 8;
        TIN v = in[(size_t)(r0 + r) * ldin + c0 + tx];
        if constexpr (sizeof(TIN) == 4) tile[r][tx] = f2bf((float)v);
        else tile[r][tx] = (u16)v;
    }
    __syncthreads();
    #pragma unroll
    for (int i = 0; i < 4; i++) {
        int r = ty + i * 8;
        out[(size_t)(c0 + r) * R + r0 + tx] = tile[tx][r];
    }
}

// ---------------- RoPE in place on [S][nh*128] bf16 (row stride ld) ----------------
__global__ void k_rope(u16* __restrict__ X, const float* __restrict__ cosT,
                       const float* __restrict__ sinT, int nh, int ld) {
    int idx = blockIdx.x * 256 + threadIdx.x;
    int d = idx & 63;
    int h = (idx >> 6) % nh;
    int s = idx / (64 * nh);
    u16* p = X + (size_t)s * ld + h * DHEAD;
    float x1 = bf2f(p[d]), x2 = bf2f(p[d + 64]);
    float c1 = cosT[s * DHEAD + d],      s1 = sinT[s * DHEAD + d];
    float c2 = cosT[s * DHEAD + d + 64], s2 = sinT[s * DHEAD + d + 64];
    p[d]      = f2bf(x1 * c1 - x2 * s1);
    p[d + 64] = f2bf(x2 * c2 + x1 * s2);
}

typedef const __attribute__((address_space(1))) u32 GBUF;
typedef __attribute__((address_space(3))) u32 LBUF;

// ---------------- m97-structure 128x128 GEMM, BK=64, swizzled LDS (R7-verified) ----
template<typename OUT_T>
__global__ __launch_bounds__(256)
void k_gemm_bt2(const u16* __restrict__ A, const u16* __restrict__ Bt,
                OUT_T* __restrict__ C, int M, int N, int K) {
    __shared__ __align__(16) u16 As[128 * 64];
    __shared__ __align__(16) u16 Bs[128 * 64];
    const int m0 = blockIdx.y * 128, n0 = blockIdx.x * 128;
    const int tid = threadIdx.x, lane = tid & 63, wid = tid >> 6;
    const int wr = wid >> 1, wc = wid & 1;
    const int g = lane >> 4, lr = lane & 15;

    const u16* sA[4]; const u16* sB[4]; u32 dste[4];
    #pragma unroll
    for (int j = 0; j < 4; j++) {
        int c = j * 256 + tid;
        int row = c >> 3;
        int colsw = (c & 7) ^ (row & 7);
        sA[j] = A  + (size_t)(m0 + row) * K + colsw * 8;
        sB[j] = Bt + (size_t)(n0 + row) * K + colsw * 8;
        dste[j] = (u32)c * 8;
    }
    auto rdoff = [&](int row, int kk) -> u32 {
        return (u32)(row * 128 + ((((kk << 2) + g) ^ (row & 7)) << 4));
    };

    f32x4 acc[4][4] = {};

    for (int k0 = 0; k0 < K; k0 += 64) {
        __syncthreads();
        #pragma unroll
        for (int j = 0; j < 4; j++)
            __builtin_amdgcn_global_load_lds((GBUF*)(sA[j] + k0), (LBUF*)(As + dste[j]), 16, 0, 0);
        #pragma unroll
        for (int j = 0; j < 4; j++)
            __builtin_amdgcn_global_load_lds((GBUF*)(sB[j] + k0), (LBUF*)(Bs + dste[j]), 16, 0, 0);
        __syncthreads();

        bf16x8 af[4][2], bfv[4][2];
        #pragma unroll
        for (int i = 0; i < 4; i++)
            #pragma unroll
            for (int kk = 0; kk < 2; kk++)
                af[i][kk] = ld_bf8((const char*)As + rdoff(wr * 64 + i * 16 + lr, kk));
        #pragma unroll
        for (int n = 0; n < 4; n++)
            #pragma unroll
            for (int kk = 0; kk < 2; kk++)
                bfv[n][kk] = ld_bf8((const char*)Bs + rdoff(wc * 64 + n * 16 + lr, kk));
        #pragma unroll
        for (int i = 0; i < 4; i++)
            #pragma unroll
            for (int n = 0; n < 4; n++)
                #pragma unroll
                for (int kk = 0; kk < 2; kk++)
                    acc[i][n] = __builtin_amdgcn_mfma_f32_16x16x32_bf16(
                        af[i][kk], bfv[n][kk], acc[i][n], 0, 0, 0);
    }
    #pragma unroll
    for (int i = 0; i < 4; i++)
        #pragma unroll
        for (int n = 0; n < 4; n++)
            #pragma unroll
            for (int r = 0; r < 4; r++) {
                int row = m0 + wr * 64 + i * 16 + g * 4 + r;
                int col = n0 + wc * 64 + n * 16 + lr;
                float v = acc[i][n][r];
                if constexpr (sizeof(OUT_T) == 2) C[(size_t)row * N + col] = f2bf(v);
                else                              C[(size_t)row * N + col] = v;
            }
}

// ---------------- attention v7: R11 core + V direct-from-L2 + K-only depth-2 prefetch ----
// R15: (a) V no longer LDS-staged (Common-mistake #7 / m169: panel 512KB is
// L2-resident; shared by 64 blocks) — halves LDS traffic + staging. Per-lane vf
// = 32B-contiguous global reads. (b) K-only 3-buffer depth-2 prefetch (48KB LDS,
// STILL 2 blocks/CU): stage K(i+2) during iter i; end-of-iter vmcnt(4) drains
// exactly K(i+1) (~2 iters old). WAR on buf (i+2)%3: protected by iter-(i-1)
// lgkmcnt(0)+barrier. Tail iters (no stage): vmcnt(4) still drains K(i+1)
// (FIFO retire: 16 newer vf ops force it). (c) core math identical to R11/R14.
__global__ __launch_bounds__(256, 2)
void k_attn3(const u16* __restrict__ Qb, const u16* __restrict__ Kb,
             const u16* __restrict__ VbT, u16* __restrict__ Ab) {
    extern __shared__ __align__(16) char smem[];

    const int bid = blockIdx.x;
    const int idx = bid & 255;
    int t = idx & 7; if (bid >> 8) t = 15 - t;
    const int h = idx >> 3, hk = h >> 2;
    const int tid = threadIdx.x, lane = tid & 63, wid = tid >> 6;
    const int ql = lane & 31, hi = lane >> 5;
    const float scale = 0.08838834764831845f;  // 1/sqrt(128)
    const int NIT = 2 * t + 2;                 // >= 2 always
    const int q0w = 128 * t + 32 * wid;
    const int qg = q0w + ql;

    const int krow_l = lane >> 4, kc16 = lane & 15;

    // K-only staging: buf in {0,1,2}, 16 KB each
    auto stage = [&](int buf, int k0) {
        u16* KsD = (u16*)(smem + buf * 16384);
        #pragma unroll
        for (int j = 0; j < 4; j++) {
            int rowt = wid * 16 + j * 4 + krow_l;
            int c16  = kc16 ^ (rowt & 7);
            __builtin_amdgcn_global_load_lds(
                (GBUF*)(Kb + (size_t)(k0 + rowt) * LDQK + hk * DHEAD + c16 * 8),
                (LBUF*)(KsD + (wid * 16 + j * 4) * 128), 16, 0, 0);
        }
    };

    bf16x8 qf[8];
    {
        const u16* qrow = Qb + (size_t)qg * LDQK + h * DHEAD;
        #pragma unroll
        for (int dc = 0; dc < 8; dc++)
            qf[dc] = ld_bf8(qrow + dc * 16 + hi * 8);
    }
    const u16* Vg = VbT + (size_t)(hk * DHEAD) * S_LEN;   // [128][2048] panel

    f32x16 acc[4] = {};
    float m = -1e30f, lsum = 0.f;
    const int imax = 2 * t + (wid >> 1);

    // prologue: K0, K1 in flight; vmcnt(4) drains qf(8) + K0(4), K1 flying
    stage(0, 0);
    stage(1, 64);
    __builtin_amdgcn_sched_barrier(0);
    asm volatile("s_waitcnt vmcnt(4)" ::: "memory");
    __builtin_amdgcn_sched_barrier(0);
    __builtin_amdgcn_s_barrier();

    for (int i = 0; i < NIT; i++) {
        if (i + 2 < NIT) stage((i + 2) % 3, (i + 2) * 64);

        if (i <= imax) {
            const char* KsB = smem + (i % 3) * 16384;

            // ---- QK^T swapped: S[k][q], two 32-kv groups ----
            f32x16 s0 = {}, s1 = {};
            __builtin_amdgcn_s_setprio(1);
            #pragma unroll
            for (int dc = 0; dc < 8; dc++) {
                int r0 = ql, r1 = 32 + ql;
                bf16x8 kf0 = ld_bf8(KsB + r0 * 256 + (((2 * dc + hi) ^ (r0 & 7)) << 4));
                bf16x8 kf1 = ld_bf8(KsB + r1 * 256 + (((2 * dc + hi) ^ (r1 & 7)) << 4));
                s0 = __builtin_amdgcn_mfma_f32_32x32x16_bf16(kf0, qf[dc], s0, 0, 0, 0);
                s1 = __builtin_amdgcn_mfma_f32_32x32x16_bf16(kf1, qf[dc], s1, 0, 0, 0);
            }
            __builtin_amdgcn_s_setprio(0);

            // ---- scale + causal mask, in place ----
            bool diag = (64 * i + 63 > q0w);
            #pragma unroll
            for (int r = 0; r < 16; r++) {
                int kloc = (r & 3) + 8 * (r >> 2) + 4 * hi;
                float v0 = s0[r] * scale, v1 = s1[r] * scale;
                if (diag) {
                    int kg = 64 * i + kloc;
                    if (kg > qg) v0 = -1e30f;
                    if (kg + 32 > qg) v1 = -1e30f;
                }
                s0[r] = v0; s1[r] = v1;
            }

            // ---- tree max over 32 + partner exchange ----
            float t8[8];
            #pragma unroll
            for (int z = 0; z < 8; z++)
                t8[z] = fmaxf(fmaxf(s0[2 * z], s0[2 * z + 1]),
                              fmaxf(s1[2 * z], s1[2 * z + 1]));
            float mx = fmaxf(fmaxf(fmaxf(t8[0], t8[1]), fmaxf(t8[2], t8[3])),
                             fmaxf(fmaxf(t8[4], t8[5]), fmaxf(t8[6], t8[7])));
            mx = fmaxf(mx, __shfl_xor(mx, 32, 64));
            bool sk = (mx <= m + 8.0f);             // defer-max (T13)
            float mn = sk ? m : mx;
            float corr = sk ? 1.0f : __expf(m - mn);
            m = mn;

            // ---- exp in place + 4-partial sum ----
            float ts0 = 0.f, ts1 = 0.f, ts2 = 0.f, ts3 = 0.f;
            #pragma unroll
            for (int z = 0; z < 8; z++) {
                s0[z]     = __expf(s0[z]     - mn); ts0 += s0[z];
                s0[z + 8] = __expf(s0[z + 8] - mn); ts1 += s0[z + 8];
                s1[z]     = __expf(s1[z]     - mn); ts2 += s1[z];
                s1[z + 8] = __expf(s1[z + 8] - mn); ts3 += s1[z + 8];
            }
            float ts = (ts0 + ts1) + (ts2 + ts3);
            ts += __shfl_xor(ts, 32, 64);
            lsum = lsum * corr + ts;
            if (!__all(sk)) {                       // rare rescale
                #pragma unroll
                for (int r = 0; r < 16; r++) {
                    float c = __shfl(corr, (r & 3) + 8 * (r >> 2) + 4 * hi, 64);
                    acc[0][r] *= c; acc[1][r] *= c; acc[2][r] *= c; acc[3][r] *= c;
                }
            }

            // ---- pack P -> PV A-fragments, windowed (cvt_pk + shfl_xor) ----
            bf16x8 pf[4];
            #pragma unroll
            for (int g2 = 0; g2 < 2; g2++)
                #pragma unroll
                for (int ksl = 0; ksl < 2; ksl++) {
                    u32 ua0, ua1, ua2, ua3;
                    {
                        float a0 = g2 ? s1[8 * ksl + 0] : s0[8 * ksl + 0];
                        float a1 = g2 ? s1[8 * ksl + 1] : s0[8 * ksl + 1];
                        float a2 = g2 ? s1[8 * ksl + 2] : s0[8 * ksl + 2];
                        float a3 = g2 ? s1[8 * ksl + 3] : s0[8 * ksl + 3];
                        float a4 = g2 ? s1[8 * ksl + 4] : s0[8 * ksl + 4];
                        float a5 = g2 ? s1[8 * ksl + 5] : s0[8 * ksl + 5];
                        float a6 = g2 ? s1[8 * ksl + 6] : s0[8 * ksl + 6];
                        float a7 = g2 ? s1[8 * ksl + 7] : s0[8 * ksl + 7];
                        asm("v_cvt_pk_bf16_f32 %0, %1, %2" : "=v"(ua0) : "v"(a0), "v"(a1));
                        asm("v_cvt_pk_bf16_f32 %0, %1, %2" : "=v"(ua1) : "v"(a2), "v"(a3));
                        asm("v_cvt_pk_bf16_f32 %0, %1, %2" : "=v"(ua2) : "v"(a4), "v"(a5));
                        asm("v_cvt_pk_bf16_f32 %0, %1, %2" : "=v"(ua3) : "v"(a6), "v"(a7));
                    }
                    u32 sa0 = __shfl_xor(ua0, 32, 64), sa1 = __shfl_xor(ua1, 32, 64);
                    u32 sa2 = __shfl_xor(ua2, 32, 64), sa3 = __shfl_xor(ua3, 32, 64);
                    int4 w4 = hi ? make_int4(sa2, sa3, ua2, ua3)
                                 : make_int4(ua0, ua1, sa0, sa1);
                    pf[2 * g2 + ksl] = __builtin_bit_cast(bf16x8, w4);
                }

            // ---- PV: acc[db] += P(32q x 64k) * V(64k x 32d), V direct from L2 ----
            __builtin_amdgcn_s_setprio(1);
            #pragma unroll
            for (int db = 0; db < 4; db++) {
                const u16* Vr = Vg + (size_t)(32 * db + ql) * S_LEN + 64 * i + hi * 8;
                #pragma unroll
                for (int ks = 0; ks < 4; ks++) {
                    bf16x8 vf = ld_bf8(Vr + ks * 16);
                    acc[db] = __builtin_amdgcn_mfma_f32_32x32x16_bf16(pf[ks], vf, acc[db], 0, 0, 0);
                }
            }
            __builtin_amdgcn_s_setprio(0);
        }

        if (i + 1 < NIT) {
            asm volatile("s_waitcnt lgkmcnt(0)" ::: "memory");
            __builtin_amdgcn_sched_barrier(0);
            asm volatile("s_waitcnt vmcnt(4)" ::: "memory");
            __builtin_amdgcn_sched_barrier(0);
            __builtin_amdgcn_s_barrier();
        }
    }

    // ---- epilogue: per-row scalar reciprocal ----
    #pragma unroll
    for (int r = 0; r < 16; r++) {
        int crow = (r & 3) + 8 * (r >> 2) + 4 * hi;
        float riv = 1.0f / __shfl(lsum, crow, 64);
        #pragma unroll
        for (int db = 0; db < 4; db++)
            Ab[(size_t)(q0w + crow) * DMODEL + h * DHEAD + db * 32 + ql]
                = f2bf(acc[db][r] * riv);
    }
}

extern "C" void kernel_launch(void* const* d_in, const int* in_sizes, int n_in,
                              void* d_out, int out_size, void* d_ws, size_t ws_size,
                              hipStream_t stream) {
    const float* hidden = (const float*)d_in[0];
    const float* cosT   = (const float*)d_in[1];
    const float* sinT   = (const float*)d_in[2];
    // d_in[3] attention_mask: known causal, implemented directly
    const float* Wq = (const float*)d_in[4];
    const float* Wk = (const float*)d_in[5];
    const float* Wv = (const float*)d_in[6];
    const float* Wo = (const float*)d_in[7];
    float* out = (float*)d_out;
    char* ws = (char*)d_ws;

    u16* Xbf   = (u16*)ws;
    u16* WqkvT = (u16*)(ws + (16u << 20));
    u16* VbT   = (u16*)(ws + (16u << 20));          // alias: valid after QKV GEMM
    u16* WoT   = (u16*)(ws + (64u << 20));
    u16* QKVb  = (u16*)(ws + (96u << 20));
    u16* Ab    = Xbf;

    k_cvt<<<dim3((S_LEN * DMODEL / 8) / 256), 256, 0, stream>>>(hidden, Xbf, S_LEN * DMODEL / 8);
    k_transpose_w<<<dim3(4096 / 64, 4096 / 64), 256, 0, stream>>>(Wq, WqkvT, 4096, 4096);
    k_transpose_w<<<dim3(1024 / 64, 4096 / 64), 256, 0, stream>>>(Wk, WqkvT + (size_t)4096 * 4096, 4096, 1024);
    k_transpose_w<<<dim3(1024 / 64, 4096 / 64), 256, 0, stream>>>(Wv, WqkvT + (size_t)5120 * 4096, 4096, 1024);
    k_transpose_w<<<dim3(4096 / 64, 4096 / 64), 256, 0, stream>>>(Wo, WoT, 4096, 4096);

    // fused QKV projection: [2048][4096] x [6144][4096]^T -> [2048][6144]
    k_gemm_bt2<u16><<<dim3(6144 / 128, 2048 / 128), 256, 0, stream>>>(Xbf, WqkvT, QKVb, 2048, 6144, 4096);

    // RoPE on Q (cols 0..4095) and K (cols 4096..5119)
    k_rope<<<(2048 * 32 * 64) / 256, 256, 0, stream>>>(QKVb, cosT, sinT, 32, LDQK);
    k_rope<<<(2048 * 8 * 64) / 256, 256, 0, stream>>>(QKVb + 4096, cosT, sinT, 8, LDQK);

    // V^T (cols 5120..6143 of QKVb) -> VbT [1024][2048]
    k_transpose_bf16<u16><<<dim3(1024 / 32, 2048 / 32), 256, 0, stream>>>(QKVb + 5120, VbT, 2048, 1024, LDQK);

    // attention v7: 512 blocks (t anti-correlated), 48 KB dynamic LDS (2 blocks/CU)
    hipFuncSetAttribute((const void*)k_attn3, hipFuncAttributeMaxDynamicSharedMemorySize, 49152);
    k_attn3<<<dim3(512), 256, 49152, stream>>>(QKVb, QKVb + 4096, VbT, Ab);

    // output projection (fp32 out)
    k_gemm_bt2<float><<<dim3(4096 / 128, 2048 / 128), 256, 0, stream>>>(Ab, WoT, out, 2048, 4096, 4096);
}

// Round 16
// 359.406 us; speedup vs baseline: 1.1465x; 1.1465x over previous
//
#include <hip/hip_runtime.h>
#include <hip/hip_bf16.h>
#include <stdint.h>

typedef unsigned short u16;
typedef unsigned int u32;
typedef __bf16 bf16x8 __attribute__((ext_vector_type(8)));
typedef float f32x4 __attribute__((ext_vector_type(4)));
typedef float f32x16 __attribute__((ext_vector_type(16)));
typedef u16 u16x8 __attribute__((ext_vector_type(8)));

#define S_LEN 2048
#define DMODEL 4096
#define NHEADS 32
#define NKVH 8
#define DHEAD 128
#define LDQK 6144   // row stride of fused QKV activation buffer

__device__ __forceinline__ float bf2f(u16 x) {
    union { u32 i; float f; } u; u.i = ((u32)x) << 16; return u.f;
}
__device__ __forceinline__ u16 f2bf(float f) {
    union { float f; u32 i; } u; u.f = f;
    u32 x = u.i;
    return (u16)((x + 0x7fffu + ((x >> 16) & 1u)) >> 16);
}
__device__ __forceinline__ bf16x8 ld_bf8(const void* p) {
    int4 v = *(const int4*)p;
    return __builtin_bit_cast(bf16x8, v);
}

// ---------------- fp32 -> bf16 elementwise ----------------
__global__ void k_cvt(const float* __restrict__ in, u16* __restrict__ out, int n8) {
    int i = blockIdx.x * 256 + threadIdx.x;
    if (i >= n8) return;
    const float4* p = (const float4*)in + (size_t)i * 2;
    float4 a = p[0], b = p[1];
    u16x8 o;
    o[0]=f2bf(a.x); o[1]=f2bf(a.y); o[2]=f2bf(a.z); o[3]=f2bf(a.w);
    o[4]=f2bf(b.x); o[5]=f2bf(b.y); o[6]=f2bf(b.z); o[7]=f2bf(b.w);
    *((u16x8*)out + i) = o;
}

// ---------------- fast weight transpose: fp32 in[R][C] -> bf16 out[C][R] ----------------
__global__ __launch_bounds__(256)
void k_transpose_w(const float* __restrict__ in, u16* __restrict__ out, int R, int C) {
    __shared__ u16 tile[64][68];
    const int c0 = blockIdx.x * 64, r0 = blockIdx.y * 64;
    const int tid = threadIdx.x, lane = tid & 63, wid = tid >> 6;

    const int ch = lane & 15;
    const int rr = (lane >> 4) + wid * 4;
    #pragma unroll
    for (int it = 0; it < 4; it++) {
        int r = rr + it * 16;
        float4 v = *(const float4*)(in + (size_t)(r0 + r) * C + c0 + ch * 4);
        u16* t = &tile[r][ch * 4];
        t[0] = f2bf(v.x); t[1] = f2bf(v.y); t[2] = f2bf(v.z); t[3] = f2bf(v.w);
    }
    __syncthreads();
    const int k8 = lane & 7;
    const int cb = (lane >> 3) + wid * 8;
    #pragma unroll
    for (int it = 0; it < 2; it++) {
        int c = cb + it * 32;
        u16x8 o;
        #pragma unroll
        for (int i = 0; i < 8; i++) o[i] = tile[k8 * 8 + i][c];
        *(u16x8*)(out + (size_t)(c0 + c) * R + r0 + k8 * 8) = o;
    }
}

// ---------------- transpose u16 (V^T only) ----------------
template<typename TIN>
__global__ void k_transpose_bf16(const TIN* __restrict__ in, u16* __restrict__ out,
                                 int R, int C, int ldin) {
    __shared__ u16 tile[32][33];
    int c0 = blockIdx.x * 32, r0 = blockIdx.y * 32;
    int tx = threadIdx.x & 31, ty = threadIdx.x >> 5;
    #pragma unroll
    for (int i = 0; i < 4; i++) {
        int r = ty + i * 8;
        TIN v = in[(size_t)(r0 + r) * ldin + c0 + tx];
        if constexpr (sizeof(TIN) == 4) tile[r][tx] = f2bf((float)v);
        else tile[r][tx] = (u16)v;
    }
    __syncthreads();
    #pragma unroll
    for (int i = 0; i < 4; i++) {
        int r = ty + i * 8;
        out[(size_t)(c0 + r) * R + r0 + tx] = tile[tx][r];
    }
}

// ---------------- RoPE in place on [S][nh*128] bf16 (row stride ld) ----------------
__global__ void k_rope(u16* __restrict__ X, const float* __restrict__ cosT,
                       const float* __restrict__ sinT, int nh, int ld) {
    int idx = blockIdx.x * 256 + threadIdx.x;
    int d = idx & 63;
    int h = (idx >> 6) % nh;
    int s = idx / (64 * nh);
    u16* p = X + (size_t)s * ld + h * DHEAD;
    float x1 = bf2f(p[d]), x2 = bf2f(p[d + 64]);
    float c1 = cosT[s * DHEAD + d],      s1 = sinT[s * DHEAD + d];
    float c2 = cosT[s * DHEAD + d + 64], s2 = sinT[s * DHEAD + d + 64];
    p[d]      = f2bf(x1 * c1 - x2 * s1);
    p[d + 64] = f2bf(x2 * c2 + x1 * s2);
}

typedef const __attribute__((address_space(1))) u32 GBUF;
typedef __attribute__((address_space(3))) u32 LBUF;

// ---------------- m97-structure 128x128 GEMM, BK=64, swizzled LDS (R7-verified) ----
template<typename OUT_T>
__global__ __launch_bounds__(256)
void k_gemm_bt2(const u16* __restrict__ A, const u16* __restrict__ Bt,
                OUT_T* __restrict__ C, int M, int N, int K) {
    __shared__ __align__(16) u16 As[128 * 64];
    __shared__ __align__(16) u16 Bs[128 * 64];
    const int m0 = blockIdx.y * 128, n0 = blockIdx.x * 128;
    const int tid = threadIdx.x, lane = tid & 63, wid = tid >> 6;
    const int wr = wid >> 1, wc = wid & 1;
    const int g = lane >> 4, lr = lane & 15;

    const u16* sA[4]; const u16* sB[4]; u32 dste[4];
    #pragma unroll
    for (int j = 0; j < 4; j++) {
        int c = j * 256 + tid;
        int row = c >> 3;
        int colsw = (c & 7) ^ (row & 7);
        sA[j] = A  + (size_t)(m0 + row) * K + colsw * 8;
        sB[j] = Bt + (size_t)(n0 + row) * K + colsw * 8;
        dste[j] = (u32)c * 8;
    }
    auto rdoff = [&](int row, int kk) -> u32 {
        return (u32)(row * 128 + ((((kk << 2) + g) ^ (row & 7)) << 4));
    };

    f32x4 acc[4][4] = {};

    for (int k0 = 0; k0 < K; k0 += 64) {
        __syncthreads();
        #pragma unroll
        for (int j = 0; j < 4; j++)
            __builtin_amdgcn_global_load_lds((GBUF*)(sA[j] + k0), (LBUF*)(As + dste[j]), 16, 0, 0);
        #pragma unroll
        for (int j = 0; j < 4; j++)
            __builtin_amdgcn_global_load_lds((GBUF*)(sB[j] + k0), (LBUF*)(Bs + dste[j]), 16, 0, 0);
        __syncthreads();

        bf16x8 af[4][2], bfv[4][2];
        #pragma unroll
        for (int i = 0; i < 4; i++)
            #pragma unroll
            for (int kk = 0; kk < 2; kk++)
                af[i][kk] = ld_bf8((const char*)As + rdoff(wr * 64 + i * 16 + lr, kk));
        #pragma unroll
        for (int n = 0; n < 4; n++)
            #pragma unroll
            for (int kk = 0; kk < 2; kk++)
                bfv[n][kk] = ld_bf8((const char*)Bs + rdoff(wc * 64 + n * 16 + lr, kk));
        #pragma unroll
        for (int i = 0; i < 4; i++)
            #pragma unroll
            for (int n = 0; n < 4; n++)
                #pragma unroll
                for (int kk = 0; kk < 2; kk++)
                    acc[i][n] = __builtin_amdgcn_mfma_f32_16x16x32_bf16(
                        af[i][kk], bfv[n][kk], acc[i][n], 0, 0, 0);
    }
    #pragma unroll
    for (int i = 0; i < 4; i++)
        #pragma unroll
        for (int n = 0; n < 4; n++)
            #pragma unroll
            for (int r = 0; r < 4; r++) {
                int row = m0 + wr * 64 + i * 16 + g * 4 + r;
                int col = n0 + wc * 64 + n * 16 + lr;
                float v = acc[i][n][r];
                if constexpr (sizeof(OUT_T) == 2) C[(size_t)row * N + col] = f2bf(v);
                else                              C[(size_t)row * N + col] = v;
            }
}

// ---------------- attention v4 (R11/R14-verified, best measured): swapped-QK 32x32,
// in-register softmax, register-dieted, 2-buffer 64KB (2 blocks/CU),
// anti-correlated (t, 15-t) block pairing ----------------
__global__ __launch_bounds__(256, 2)
void k_attn3(const u16* __restrict__ Qb, const u16* __restrict__ Kb,
             const u16* __restrict__ VbT, u16* __restrict__ Ab) {
    extern __shared__ __align__(16) char smem[];

    const int bid = blockIdx.x;
    const int idx = bid & 255;
    int t = idx & 7; if (bid >> 8) t = 15 - t;
    const int h = idx >> 3, hk = h >> 2;
    const int tid = threadIdx.x, lane = tid & 63, wid = tid >> 6;
    const int ql = lane & 31, hi = lane >> 5;
    const float scale = 0.08838834764831845f;  // 1/sqrt(128)
    const int NIT = 2 * t + 2;
    const int q0w = 128 * t + 32 * wid;
    const int qg = q0w + ql;

    const int krow_l = lane >> 4, kc16 = lane & 15;
    const int vrow_l = lane >> 3, vc8  = lane & 7;

    auto stage = [&](int buf, int k0) {
        u16* KsD = (u16*)smem + buf * 8192;
        u16* VtD = (u16*)(smem + 32768) + buf * 8192;
        #pragma unroll
        for (int j = 0; j < 4; j++) {
            int rowt = wid * 16 + j * 4 + krow_l;
            int c16  = kc16 ^ (rowt & 7);
            __builtin_amdgcn_global_load_lds(
                (GBUF*)(Kb + (size_t)(k0 + rowt) * LDQK + hk * DHEAD + c16 * 8),
                (LBUF*)(KsD + (wid * 16 + j * 4) * 128), 16, 0, 0);
        }
        #pragma unroll
        for (int j = 0; j < 4; j++) {
            int rowt = wid * 32 + j * 8 + vrow_l;
            int c8   = vc8 ^ (rowt & 7);
            __builtin_amdgcn_global_load_lds(
                (GBUF*)(VbT + (size_t)(hk * DHEAD + rowt) * S_LEN + k0 + c8 * 8),
                (LBUF*)(VtD + (wid * 32 + j * 8) * 64), 16, 0, 0);
        }
    };

    bf16x8 qf[8];
    {
        const u16* qrow = Qb + (size_t)qg * LDQK + h * DHEAD;
        #pragma unroll
        for (int dc = 0; dc < 8; dc++)
            qf[dc] = ld_bf8(qrow + dc * 16 + hi * 8);
    }

    f32x16 acc[4] = {};
    float m = -1e30f, lsum = 0.f;
    const int imax = 2 * t + (wid >> 1);

    stage(0, 0);
    asm volatile("s_waitcnt vmcnt(0)" ::: "memory");
    __builtin_amdgcn_s_barrier();

    for (int i = 0; i < NIT; i++) {
        if (i + 1 < NIT) stage((i + 1) & 1, (i + 1) * 64);

        if (i <= imax) {
            const char* KsB = smem + (i & 1) * 16384;
            const char* VtB = smem + 32768 + (i & 1) * 16384;

            // ---- QK^T swapped: S[k][q], two 32-kv groups ----
            f32x16 s0 = {}, s1 = {};
            __builtin_amdgcn_s_setprio(1);
            #pragma unroll
            for (int dc = 0; dc < 8; dc++) {
                int r0 = ql, r1 = 32 + ql;
                bf16x8 kf0 = ld_bf8(KsB + r0 * 256 + (((2 * dc + hi) ^ (r0 & 7)) << 4));
                bf16x8 kf1 = ld_bf8(KsB + r1 * 256 + (((2 * dc + hi) ^ (r1 & 7)) << 4));
                s0 = __builtin_amdgcn_mfma_f32_32x32x16_bf16(kf0, qf[dc], s0, 0, 0, 0);
                s1 = __builtin_amdgcn_mfma_f32_32x32x16_bf16(kf1, qf[dc], s1, 0, 0, 0);
            }
            __builtin_amdgcn_s_setprio(0);

            // ---- scale + causal mask, in place ----
            bool diag = (64 * i + 63 > q0w);
            #pragma unroll
            for (int r = 0; r < 16; r++) {
                int kloc = (r & 3) + 8 * (r >> 2) + 4 * hi;
                float v0 = s0[r] * scale, v1 = s1[r] * scale;
                if (diag) {
                    int kg = 64 * i + kloc;
                    if (kg > qg) v0 = -1e30f;
                    if (kg + 32 > qg) v1 = -1e30f;
                }
                s0[r] = v0; s1[r] = v1;
            }

            // ---- tree max over 32 + partner exchange ----
            float t8[8];
            #pragma unroll
            for (int z = 0; z < 8; z++)
                t8[z] = fmaxf(fmaxf(s0[2 * z], s0[2 * z + 1]),
                              fmaxf(s1[2 * z], s1[2 * z + 1]));
            float mx = fmaxf(fmaxf(fmaxf(t8[0], t8[1]), fmaxf(t8[2], t8[3])),
                             fmaxf(fmaxf(t8[4], t8[5]), fmaxf(t8[6], t8[7])));
            mx = fmaxf(mx, __shfl_xor(mx, 32, 64));
            bool sk = (mx <= m + 8.0f);             // defer-max (T13)
            float mn = sk ? m : mx;
            float corr = sk ? 1.0f : __expf(m - mn);
            m = mn;

            // ---- exp in place + 4-partial sum ----
            float ts0 = 0.f, ts1 = 0.f, ts2 = 0.f, ts3 = 0.f;
            #pragma unroll
            for (int z = 0; z < 8; z++) {
                s0[z]     = __expf(s0[z]     - mn); ts0 += s0[z];
                s0[z + 8] = __expf(s0[z + 8] - mn); ts1 += s0[z + 8];
                s1[z]     = __expf(s1[z]     - mn); ts2 += s1[z];
                s1[z + 8] = __expf(s1[z + 8] - mn); ts3 += s1[z + 8];
            }
            float ts = (ts0 + ts1) + (ts2 + ts3);
            ts += __shfl_xor(ts, 32, 64);
            lsum = lsum * corr + ts;
            if (!__all(sk)) {                       // rare rescale, scalar temp
                #pragma unroll
                for (int r = 0; r < 16; r++) {
                    float c = __shfl(corr, (r & 3) + 8 * (r >> 2) + 4 * hi, 64);
                    acc[0][r] *= c; acc[1][r] *= c; acc[2][r] *= c; acc[3][r] *= c;
                }
            }

            // ---- pack P -> PV A-fragments, windowed (cvt_pk + shfl_xor) ----
            bf16x8 pf[4];
            #pragma unroll
            for (int g2 = 0; g2 < 2; g2++)
                #pragma unroll
                for (int ksl = 0; ksl < 2; ksl++) {
                    u32 ua0, ua1, ua2, ua3;
                    {
                        float a0 = g2 ? s1[8 * ksl + 0] : s0[8 * ksl + 0];
                        float a1 = g2 ? s1[8 * ksl + 1] : s0[8 * ksl + 1];
                        float a2 = g2 ? s1[8 * ksl + 2] : s0[8 * ksl + 2];
                        float a3 = g2 ? s1[8 * ksl + 3] : s0[8 * ksl + 3];
                        float a4 = g2 ? s1[8 * ksl + 4] : s0[8 * ksl + 4];
                        float a5 = g2 ? s1[8 * ksl + 5] : s0[8 * ksl + 5];
                        float a6 = g2 ? s1[8 * ksl + 6] : s0[8 * ksl + 6];
                        float a7 = g2 ? s1[8 * ksl + 7] : s0[8 * ksl + 7];
                        asm("v_cvt_pk_bf16_f32 %0, %1, %2" : "=v"(ua0) : "v"(a0), "v"(a1));
                        asm("v_cvt_pk_bf16_f32 %0, %1, %2" : "=v"(ua1) : "v"(a2), "v"(a3));
                        asm("v_cvt_pk_bf16_f32 %0, %1, %2" : "=v"(ua2) : "v"(a4), "v"(a5));
                        asm("v_cvt_pk_bf16_f32 %0, %1, %2" : "=v"(ua3) : "v"(a6), "v"(a7));
                    }
                    u32 sa0 = __shfl_xor(ua0, 32, 64), sa1 = __shfl_xor(ua1, 32, 64);
                    u32 sa2 = __shfl_xor(ua2, 32, 64), sa3 = __shfl_xor(ua3, 32, 64);
                    int4 w4 = hi ? make_int4(sa2, sa3, ua2, ua3)
                                 : make_int4(ua0, ua1, sa0, sa1);
                    pf[2 * g2 + ksl] = __builtin_bit_cast(bf16x8, w4);
                }

            // ---- PV: acc[db] += P(32q x 64k) * V(64k x 32d) ----
            __builtin_amdgcn_s_setprio(1);
            #pragma unroll
            for (int db = 0; db < 4; db++) {
                int row = 32 * db + ql;
                #pragma unroll
                for (int ks = 0; ks < 4; ks++) {
                    bf16x8 vf = ld_bf8(VtB + row * 128 + (((2 * ks + hi) ^ (row & 7)) << 4));
                    acc[db] = __builtin_amdgcn_mfma_f32_32x32x16_bf16(pf[ks], vf, acc[db], 0, 0, 0);
                }
            }
            __builtin_amdgcn_s_setprio(0);
        }

        asm volatile("s_waitcnt lgkmcnt(0)" ::: "memory");
        __builtin_amdgcn_sched_barrier(0);
        asm volatile("s_waitcnt vmcnt(0)" ::: "memory");
        __builtin_amdgcn_s_barrier();
    }

    // ---- epilogue: per-row scalar reciprocal ----
    #pragma unroll
    for (int r = 0; r < 16; r++) {
        int crow = (r & 3) + 8 * (r >> 2) + 4 * hi;
        float riv = 1.0f / __shfl(lsum, crow, 64);
        #pragma unroll
        for (int db = 0; db < 4; db++)
            Ab[(size_t)(q0w + crow) * DMODEL + h * DHEAD + db * 32 + ql]
                = f2bf(acc[db][r] * riv);
    }
}

extern "C" void kernel_launch(void* const* d_in, const int* in_sizes, int n_in,
                              void* d_out, int out_size, void* d_ws, size_t ws_size,
                              hipStream_t stream) {
    const float* hidden = (const float*)d_in[0];
    const float* cosT   = (const float*)d_in[1];
    const float* sinT   = (const float*)d_in[2];
    // d_in[3] attention_mask: known causal, implemented directly
    const float* Wq = (const float*)d_in[4];
    const float* Wk = (const float*)d_in[5];
    const float* Wv = (const float*)d_in[6];
    const float* Wo = (const float*)d_in[7];
    float* out = (float*)d_out;
    char* ws = (char*)d_ws;

    u16* Xbf   = (u16*)ws;
    u16* WqkvT = (u16*)(ws + (16u << 20));
    u16* VbT   = (u16*)(ws + (16u << 20));          // alias: valid after QKV GEMM
    u16* WoT   = (u16*)(ws + (64u << 20));
    u16* QKVb  = (u16*)(ws + (96u << 20));
    u16* Ab    = Xbf;

    k_cvt<<<dim3((S_LEN * DMODEL / 8) / 256), 256, 0, stream>>>(hidden, Xbf, S_LEN * DMODEL / 8);
    k_transpose_w<<<dim3(4096 / 64, 4096 / 64), 256, 0, stream>>>(Wq, WqkvT, 4096, 4096);
    k_transpose_w<<<dim3(1024 / 64, 4096 / 64), 256, 0, stream>>>(Wk, WqkvT + (size_t)4096 * 4096, 4096, 1024);
    k_transpose_w<<<dim3(1024 / 64, 4096 / 64), 256, 0, stream>>>(Wv, WqkvT + (size_t)5120 * 4096, 4096, 1024);
    k_transpose_w<<<dim3(4096 / 64, 4096 / 64), 256, 0, stream>>>(Wo, WoT, 4096, 4096);

    // fused QKV projection: [2048][4096] x [6144][4096]^T -> [2048][6144]
    k_gemm_bt2<u16><<<dim3(6144 / 128, 2048 / 128), 256, 0, stream>>>(Xbf, WqkvT, QKVb, 2048, 6144, 4096);

    // RoPE on Q (cols 0..4095) and K (cols 4096..5119)
    k_rope<<<(2048 * 32 * 64) / 256, 256, 0, stream>>>(QKVb, cosT, sinT, 32, LDQK);
    k_rope<<<(2048 * 8 * 64) / 256, 256, 0, stream>>>(QKVb + 4096, cosT, sinT, 8, LDQK);

    // V^T (cols 5120..6143 of QKVb) -> VbT [1024][2048]
    k_transpose_bf16<u16><<<dim3(1024 / 32, 2048 / 32), 256, 0, stream>>>(QKVb + 5120, VbT, 2048, 1024, LDQK);

    // attention v4: 512 blocks (t anti-correlated across halves), 64 KB dynamic LDS
    hipFuncSetAttribute((const void*)k_attn3, hipFuncAttributeMaxDynamicSharedMemorySize, 65536);
    k_attn3<<<dim3(512), 256, 65536, stream>>>(QKVb, QKVb + 4096, VbT, Ab);

    // output projection (fp32 out)
    k_gemm_bt2<float><<<dim3(4096 / 128, 2048 / 128), 256, 0, stream>>>(Ab, WoT, out, 2048, 4096, 4096);
}